// Round 9
// baseline (282.674 us; speedup 1.0000x reference)
//
#include <hip/hip_runtime.h>
#include <math.h>

#define IMG_H    512
#define IMG_W    512
#define IMG_HW   (IMG_H * IMG_W)
#define N_IMG    128
#define NSTRIPS  16
#define NBINS    256
#define DELTA    8     // fill target = img - DELTA (mod 128)

typedef float f32x4 __attribute__((ext_vector_type(4)));

// ---------------------------------------------------------------------------
// Fused hist+fill, role-shifted: 2048 blocks = 128 images x 16 strips.
// Phase 1 (per block): R7's bank-conflict-free lane-column LDS histogram of
//   its 32-row strip; store 256-bin partial; release-ticket done[img].
// Phase 2 (same block): become the fill block for image (img-8)&127, whose
//   histogram completed earlier in dispatch order: spin (relaxed + s_sleep,
//   lane 0 only), one acquire fence, redundantly reduce that image's 16
//   partials to the entropy scalar, then NT-fill 1/16 of its output slice.
// Gen-1 blocks (1280 resident, LDS-limited 5/CU) finish hist ~25us and their
// fills (HBM writes) overlap gen-2's hist (DS-pipe work) -> read+DS phase
// and write phase pipeline instead of serializing.
// Deadlock-free: dispatch is ascending; only imgs 0..7's blocks (128) can
// spin long, far below the 1280 residency.
// ---------------------------------------------------------------------------
__global__ __launch_bounds__(256) void glcm_fused_kernel(
    const float* __restrict__ x, float* __restrict__ out,
    unsigned int* __restrict__ partial, unsigned int* __restrict__ done) {

    constexpr int ROWS  = IMG_H / NSTRIPS;   // 32
    constexpr int ITERS = ROWS / 2;          // 16

    __shared__ unsigned int lh[128 * 64];    // 32 KB: 128 bin-pairs x 64 lanes
    __shared__ float psum[4];
    __shared__ float ent_s;

    const int tid   = threadIdx.x;
    const int lane  = tid & 63;
    const int bid   = blockIdx.x;
    const int img   = bid >> 4;
    const int strip = bid & 15;

    #pragma unroll
    for (int i = tid; i < 128 * 64; i += 256) lh[i] = 0u;
    __syncthreads();

    const float* __restrict__ base = x + (size_t)img * IMG_HW;

    // 256 threads cover 2 rows per iteration, 4 pixels per thread.
    const int half = tid >> 7;            // which of the two rows
    const int jj   = (tid & 127) << 2;    // first column [0..508]
    const int jm1  = (jj + IMG_W - 1) & (IMG_W - 1);
    const int jp4  = (jj + 4) & (IMG_W - 1);
    const int rowBase = strip * ROWS;

    float4 c4, u4; float cm1, um1, up4;
    {   // prologue load (it = 0)
        const int r  = rowBase + half;
        const int ru = (r + IMG_H - 1) & (IMG_H - 1);
        c4  = *reinterpret_cast<const float4*>(base + (size_t)r  * IMG_W + jj);
        u4  = *reinterpret_cast<const float4*>(base + (size_t)ru * IMG_W + jj);
        cm1 = base[(size_t)r  * IMG_W + jm1];
        um1 = base[(size_t)ru * IMG_W + jm1];
        up4 = base[(size_t)ru * IMG_W + jp4];
    }

    for (int it = 0; it < ITERS; ++it) {
        float4 nc4, nu4; float ncm1, num1, nup4;
        if (it + 1 < ITERS) {             // prefetch next row pair
            const int r  = rowBase + (it + 1) * 2 + half;
            const int ru = (r + IMG_H - 1) & (IMG_H - 1);
            nc4  = *reinterpret_cast<const float4*>(base + (size_t)r  * IMG_W + jj);
            nu4  = *reinterpret_cast<const float4*>(base + (size_t)ru * IMG_W + jj);
            ncm1 = base[(size_t)r  * IMG_W + jm1];
            num1 = base[(size_t)ru * IMG_W + jm1];
            nup4 = base[(size_t)ru * IMG_W + jp4];
        }

        int qc[5];   // qc[0]=left-of-first, qc[1..4]=the 4 pixels
        int qu[6];   // qu[0]=up-left, qu[1..4]=up row, qu[5]=up-right-of-last
        qc[0] = (int)(cm1 * 15.0f);
        qc[1] = (int)(c4.x * 15.0f); qc[2] = (int)(c4.y * 15.0f);
        qc[3] = (int)(c4.z * 15.0f); qc[4] = (int)(c4.w * 15.0f);
        qu[0] = (int)(um1 * 15.0f);
        qu[1] = (int)(u4.x * 15.0f); qu[2] = (int)(u4.y * 15.0f);
        qu[3] = (int)(u4.z * 15.0f); qu[4] = (int)(u4.w * 15.0f);
        qu[5] = (int)(up4 * 15.0f);

        // word = ((q&7)*16 + s)*64 + lane, field = q>>3 (bank == lane%32)
        #pragma unroll
        for (int k = 0; k < 4; ++k) {
            const int q = qc[k + 1];
            const int kb = ((q & 7) << 10) + lane;
            const unsigned int val = 1u << ((q & 8) << 1);
            atomicAdd(&lh[kb + (qc[k]     << 6)], val);  // angle   0 (left)
            atomicAdd(&lh[kb + (qu[k + 2] << 6)], val);  // angle  45 (up-right)
            atomicAdd(&lh[kb + (qu[k + 1] << 6)], val);  // angle  90 (up)
            atomicAdd(&lh[kb + (qu[k]     << 6)], val);  // angle 135 (up-left)
        }

        c4 = nc4; u4 = nu4; cm1 = ncm1; um1 = num1; up4 = nup4;
    }

    __syncthreads();
    // Merge: thread t sums pair-column p = t&127 over lane half (t>>7).
    // p = (q&7)*16+s: low field -> bin p, high field -> bin p+128.
    const int p  = tid & 127;
    const int hf = tid >> 7;
    unsigned int slo = 0, shi = 0;
    #pragma unroll
    for (int i = 0; i < 32; ++i) {
        const int l = (hf << 5) + ((p + i) & 31);
        const unsigned int w = lh[(p << 6) + l];
        slo += w & 0xffffu;
        shi += w >> 16;
    }
    __syncthreads();                 // lh reads done; reuse lh[0..255] as scratch
    if (hf) { lh[p] = slo; lh[128 + p] = shi; }
    __syncthreads();
    if (!hf) {
        const size_t ob = (size_t)(img * NSTRIPS + strip) * NBINS;
        partial[ob + p]       = slo + lh[p];
        partial[ob + 128 + p] = shi + lh[128 + p];
    }
    __syncthreads();

    if (tid == 0) {
        __threadfence();                               // release partial stores
        __hip_atomic_fetch_add(&done[img], 1u,
                               __ATOMIC_RELEASE, __HIP_MEMORY_SCOPE_AGENT);
    }

    // ---- Phase 2: fill image (img - DELTA) mod 128, sub-slice = strip ----
    const int timg = (img + N_IMG - DELTA) & (N_IMG - 1);

    if (tid == 0) {
        while (__hip_atomic_load(&done[timg], __ATOMIC_RELAXED,
                                 __HIP_MEMORY_SCOPE_AGENT) < NSTRIPS)
            __builtin_amdgcn_s_sleep(32);
        __threadfence();                               // acquire partials
    }
    __syncthreads();

    // entropy of timg from its 16 strip partials (relaxed atomic loads -> L2)
    unsigned int c = 0;
    #pragma unroll
    for (int s = 0; s < NSTRIPS; ++s)
        c += __hip_atomic_load(&partial[(size_t)(timg * NSTRIPS + s) * NBINS + tid],
                               __ATOMIC_RELAXED, __HIP_MEMORY_SCOPE_AGENT);
    const float pr = (float)c * (1.0f / 1048576.0f);   // sum == 2^20 exact
    float t = pr * logf(pr + 1e-10f);
    #pragma unroll
    for (int off = 32; off > 0; off >>= 1) t += __shfl_down(t, off, 64);
    if ((tid & 63) == 0) psum[tid >> 6] = t;
    __syncthreads();
    if (tid == 0) ent_s = -(psum[0] + psum[1] + psum[2] + psum[3]);
    __syncthreads();

    const float e = ent_s;
    const f32x4 v = {e, e, e, e};
    f32x4* ob = reinterpret_cast<f32x4*>(out) +
                (size_t)timg * (IMG_HW / 4) + (size_t)strip * (IMG_HW / 4 / NSTRIPS);
    #pragma unroll
    for (int i = tid; i < IMG_HW / 4 / NSTRIPS; i += 256)   // 16 NT stores/thread
        __builtin_nontemporal_store(v, ob + i);
}

extern "C" void kernel_launch(void* const* d_in, const int* in_sizes, int n_in,
                              void* d_out, int out_size, void* d_ws, size_t ws_size,
                              hipStream_t stream) {
    const float* x = (const float*)d_in[0];
    float* out = (float*)d_out;

    unsigned int* partial = (unsigned int*)d_ws;            // 128*16*256 u32 = 2 MB
    unsigned int* done = partial + (size_t)N_IMG * NSTRIPS * NBINS;  // 128 u32

    // done[] must start at zero every call
    (void)hipMemsetAsync(done, 0, N_IMG * sizeof(unsigned int), stream);

    glcm_fused_kernel<<<N_IMG * NSTRIPS, 256, 0, stream>>>(x, out, partial, done);
}

// Round 10
// 73.804 us; speedup vs baseline: 3.8301x; 3.8301x over previous
//
#include <hip/hip_runtime.h>
#include <math.h>

#define IMG_H    512
#define IMG_W    512
#define IMG_HW   (IMG_H * IMG_W)
#define N_IMG    128
#define NSTRIPS  16
#define NBINS    256
#define DELTA    8            // fill target = img - DELTA (mod 128)
#define SENTINEL 0xFFFFFFFFu  // partial counts are <= 65536, so this is safe

typedef float f32x4 __attribute__((ext_vector_type(4)));

// ---------------------------------------------------------------------------
// Fused hist+fill with FENCE-FREE sentinel handoff.
// 2048 blocks = 128 images x 16 strips, 256 threads.
//
// Phase 1: R7's bank-conflict-free lane-column LDS histogram (packed 2x16-bit,
//   word = ((q&7)*16+s)*64+lane, field = q>>3; bank == lane%32, data-
//   independent). Publish the 256 strip-partial bins with RELAXED AGENT-scope
//   atomic stores (per-access coherence -> no threadfence / cache flush; R3 &
//   R9 showed per-block agent fences cost ~75ns each at the TCC = 5x blowup).
// Phase 2: same block becomes the fill block for image (img-DELTA)&127:
//   each thread polls its 16 partial words (relaxed agent atomic loads) until
//   != SENTINEL — every word is its own ready flag, so no ordering is needed
//   anywhere. Then redundant entropy reduce + NT-fill of 1/16 slice.
// Deadlock-free: 1024 blocks resident (32KB LDS -> 4/CU); only the 128
// wrap blocks (imgs 0..7 -> targets 120..127) spin long.
// ---------------------------------------------------------------------------
__global__ __launch_bounds__(256) void glcm_fused_kernel(
    const float* __restrict__ x, float* __restrict__ out,
    unsigned int* __restrict__ partial) {

    constexpr int ROWS  = IMG_H / NSTRIPS;   // 32
    constexpr int ITERS = ROWS / 2;          // 16

    __shared__ unsigned int lh[128 * 64];    // 32 KB: 128 bin-pairs x 64 lanes
    __shared__ float psum[4];
    __shared__ float ent_s;

    const int tid   = threadIdx.x;
    const int lane  = tid & 63;
    const int bid   = blockIdx.x;
    const int img   = bid >> 4;
    const int strip = bid & 15;

    #pragma unroll
    for (int i = tid; i < 128 * 64; i += 256) lh[i] = 0u;
    __syncthreads();

    const float* __restrict__ base = x + (size_t)img * IMG_HW;

    // 256 threads cover 2 rows per iteration, 4 pixels per thread.
    const int half = tid >> 7;            // which of the two rows
    const int jj   = (tid & 127) << 2;    // first column [0..508]
    const int jm1  = (jj + IMG_W - 1) & (IMG_W - 1);
    const int jp4  = (jj + 4) & (IMG_W - 1);
    const int rowBase = strip * ROWS;

    float4 c4, u4; float cm1, um1, up4;
    {   // prologue load (it = 0)
        const int r  = rowBase + half;
        const int ru = (r + IMG_H - 1) & (IMG_H - 1);
        c4  = *reinterpret_cast<const float4*>(base + (size_t)r  * IMG_W + jj);
        u4  = *reinterpret_cast<const float4*>(base + (size_t)ru * IMG_W + jj);
        cm1 = base[(size_t)r  * IMG_W + jm1];
        um1 = base[(size_t)ru * IMG_W + jm1];
        up4 = base[(size_t)ru * IMG_W + jp4];
    }

    for (int it = 0; it < ITERS; ++it) {
        float4 nc4, nu4; float ncm1, num1, nup4;
        if (it + 1 < ITERS) {             // prefetch next row pair
            const int r  = rowBase + (it + 1) * 2 + half;
            const int ru = (r + IMG_H - 1) & (IMG_H - 1);
            nc4  = *reinterpret_cast<const float4*>(base + (size_t)r  * IMG_W + jj);
            nu4  = *reinterpret_cast<const float4*>(base + (size_t)ru * IMG_W + jj);
            ncm1 = base[(size_t)r  * IMG_W + jm1];
            num1 = base[(size_t)ru * IMG_W + jm1];
            nup4 = base[(size_t)ru * IMG_W + jp4];
        }

        int qc[5];   // qc[0]=left-of-first, qc[1..4]=the 4 pixels
        int qu[6];   // qu[0]=up-left, qu[1..4]=up row, qu[5]=up-right-of-last
        qc[0] = (int)(cm1 * 15.0f);
        qc[1] = (int)(c4.x * 15.0f); qc[2] = (int)(c4.y * 15.0f);
        qc[3] = (int)(c4.z * 15.0f); qc[4] = (int)(c4.w * 15.0f);
        qu[0] = (int)(um1 * 15.0f);
        qu[1] = (int)(u4.x * 15.0f); qu[2] = (int)(u4.y * 15.0f);
        qu[3] = (int)(u4.z * 15.0f); qu[4] = (int)(u4.w * 15.0f);
        qu[5] = (int)(up4 * 15.0f);

        // word = ((q&7)*16 + s)*64 + lane, field = q>>3 (bank == lane%32)
        #pragma unroll
        for (int k = 0; k < 4; ++k) {
            const int q = qc[k + 1];
            const int kb = ((q & 7) << 10) + lane;
            const unsigned int val = 1u << ((q & 8) << 1);
            atomicAdd(&lh[kb + (qc[k]     << 6)], val);  // angle   0 (left)
            atomicAdd(&lh[kb + (qu[k + 2] << 6)], val);  // angle  45 (up-right)
            atomicAdd(&lh[kb + (qu[k + 1] << 6)], val);  // angle  90 (up)
            atomicAdd(&lh[kb + (qu[k]     << 6)], val);  // angle 135 (up-left)
        }

        c4 = nc4; u4 = nu4; cm1 = ncm1; um1 = num1; up4 = nup4;
    }

    __syncthreads();
    // Merge: thread t sums pair-column p = t&127 over lane half (t>>7).
    // p = (q&7)*16+s: low field -> bin p, high field -> bin p+128.
    const int p  = tid & 127;
    const int hf = tid >> 7;
    unsigned int slo = 0, shi = 0;
    #pragma unroll
    for (int i = 0; i < 32; ++i) {
        const int l = (hf << 5) + ((p + i) & 31);
        const unsigned int w = lh[(p << 6) + l];
        slo += w & 0xffffu;
        shi += w >> 16;
    }
    __syncthreads();                 // lh reads done; reuse lh[0..255] as scratch
    if (hf) { lh[p] = slo; lh[128 + p] = shi; }
    __syncthreads();
    if (!hf) {
        // publish: relaxed agent-scope atomic stores (coherent, NO fence)
        const size_t ob = (size_t)(img * NSTRIPS + strip) * NBINS;
        __hip_atomic_store(&partial[ob + p],       slo + lh[p],
                           __ATOMIC_RELAXED, __HIP_MEMORY_SCOPE_AGENT);
        __hip_atomic_store(&partial[ob + 128 + p], shi + lh[128 + p],
                           __ATOMIC_RELAXED, __HIP_MEMORY_SCOPE_AGENT);
    }

    // ---- Phase 2: fill image (img - DELTA) mod 128, sub-slice = strip ----
    const int timg = (img + N_IMG - DELTA) & (N_IMG - 1);

    // each thread polls its 16 partial words; every word is its own flag
    unsigned int c = 0;
    #pragma unroll
    for (int s = 0; s < NSTRIPS; ++s) {
        const unsigned int* ap =
            &partial[(size_t)(timg * NSTRIPS + s) * NBINS + tid];
        unsigned int w;
        while ((w = __hip_atomic_load(ap, __ATOMIC_RELAXED,
                                      __HIP_MEMORY_SCOPE_AGENT)) == SENTINEL)
            __builtin_amdgcn_s_sleep(8);
        c += w;
    }

    const float pr = (float)c * (1.0f / 1048576.0f);   // sum == 2^20 exact
    float t = pr * logf(pr + 1e-10f);
    #pragma unroll
    for (int off = 32; off > 0; off >>= 1) t += __shfl_down(t, off, 64);
    if ((tid & 63) == 0) psum[tid >> 6] = t;
    __syncthreads();
    if (tid == 0) ent_s = -(psum[0] + psum[1] + psum[2] + psum[3]);
    __syncthreads();

    const float e = ent_s;
    const f32x4 v = {e, e, e, e};
    f32x4* ob4 = reinterpret_cast<f32x4*>(out) +
                 (size_t)timg * (IMG_HW / 4) + (size_t)strip * (IMG_HW / 4 / NSTRIPS);
    #pragma unroll
    for (int i = tid; i < IMG_HW / 4 / NSTRIPS; i += 256)   // 16 NT stores/thread
        __builtin_nontemporal_store(v, ob4 + i);
}

extern "C" void kernel_launch(void* const* d_in, const int* in_sizes, int n_in,
                              void* d_out, int out_size, void* d_ws, size_t ws_size,
                              hipStream_t stream) {
    const float* x = (const float*)d_in[0];
    float* out = (float*)d_out;

    unsigned int* partial = (unsigned int*)d_ws;   // 128*16*256 u32 = 2 MB

    // every partial word starts as SENTINEL (0xFF bytes) each call
    (void)hipMemsetAsync(partial, 0xFF,
                         (size_t)N_IMG * NSTRIPS * NBINS * sizeof(unsigned int),
                         stream);

    glcm_fused_kernel<<<N_IMG * NSTRIPS, 256, 0, stream>>>(x, out, partial);
}

// Round 11
// 63.890 us; speedup vs baseline: 4.4244x; 1.1552x over previous
//
#include <hip/hip_runtime.h>
#include <math.h>

#define IMG_H    512
#define IMG_W    512
#define IMG_HW   (IMG_H * IMG_W)
#define N_IMG    128
#define NSTRIPS  8
#define NBINS    256
#define FILL_PER_IMG 16   // fill blocks per image

typedef float f32x4 __attribute__((ext_vector_type(4)));

// ---------------------------------------------------------------------------
// Kernel 1: per-(image,strip) 256-bin joint histogram over 4 angles
// (wraparound roll semantics). 1024 blocks = 128 images x 8 strips.
//
// Bank-conflict-free LDS histogram: per-LANE columns of packed 2x16-bit
// counters, field selected by q's MSB (bin bit 7):
//   word = ((q&7)*16 + s)*64 + lane,  field = q>>3.
// bank == lane%32 -> every ds_add is exactly 2 lanes/bank (the HW minimum
// for wave64 on 32 banks) and data-independent. ds_add measured ~11.6
// cyc/waveop here = 2x ds_read_b32 throughput -> this phase is at the
// LDS-atomic RMW floor (~40us for 8192 waveops/CU). 4 increments/pixel is
// algorithmically irreducible.
// Overflow: each 16-bit field gets <= 4 threads * 512 = 2048 increments.
// NOTE (R3/R9/R10): do NOT fuse fill into this kernel. Cross-block handoff
// costs more than the overlap prize on this HW (agent fences ~75ns each at
// the TCC -> 5x blowup; fence-free sentinel polling -> uncached L2 latency
// + lock-step generations -> still slower than split).
// ---------------------------------------------------------------------------
__global__ __launch_bounds__(256) void glcm_hist_kernel(
    const float* __restrict__ x, unsigned int* __restrict__ partial) {

    constexpr int ROWS  = IMG_H / NSTRIPS;   // 64
    constexpr int ITERS = ROWS / 2;          // 32

    __shared__ unsigned int lh[128 * 64];    // 32 KB: 128 bin-pairs x 64 lanes
    const int tid   = threadIdx.x;
    const int lane  = tid & 63;
    const int bid   = blockIdx.x;
    const int img   = bid >> 3;
    const int strip = bid & 7;

    #pragma unroll
    for (int i = tid; i < 128 * 64; i += 256) lh[i] = 0u;
    __syncthreads();

    const float* __restrict__ base = x + (size_t)img * IMG_HW;

    // 256 threads cover 2 rows per iteration, 4 pixels per thread.
    const int half = tid >> 7;            // which of the two rows
    const int jj   = (tid & 127) << 2;    // first column [0..508]
    const int jm1  = (jj + IMG_W - 1) & (IMG_W - 1);
    const int jp4  = (jj + 4) & (IMG_W - 1);
    const int rowBase = strip * ROWS;

    float4 c4, u4; float cm1, um1, up4;
    {   // prologue load (it = 0)
        const int r  = rowBase + half;
        const int ru = (r + IMG_H - 1) & (IMG_H - 1);
        c4  = *reinterpret_cast<const float4*>(base + (size_t)r  * IMG_W + jj);
        u4  = *reinterpret_cast<const float4*>(base + (size_t)ru * IMG_W + jj);
        cm1 = base[(size_t)r  * IMG_W + jm1];
        um1 = base[(size_t)ru * IMG_W + jm1];
        up4 = base[(size_t)ru * IMG_W + jp4];
    }

    for (int it = 0; it < ITERS; ++it) {
        float4 nc4, nu4; float ncm1, num1, nup4;
        if (it + 1 < ITERS) {             // prefetch next row pair
            const int r  = rowBase + (it + 1) * 2 + half;
            const int ru = (r + IMG_H - 1) & (IMG_H - 1);
            nc4  = *reinterpret_cast<const float4*>(base + (size_t)r  * IMG_W + jj);
            nu4  = *reinterpret_cast<const float4*>(base + (size_t)ru * IMG_W + jj);
            ncm1 = base[(size_t)r  * IMG_W + jm1];
            num1 = base[(size_t)ru * IMG_W + jm1];
            nup4 = base[(size_t)ru * IMG_W + jp4];
        }

        int qc[5];   // qc[0]=left-of-first, qc[1..4]=the 4 pixels
        int qu[6];   // qu[0]=up-left, qu[1..4]=up row, qu[5]=up-right-of-last
        qc[0] = (int)(cm1 * 15.0f);
        qc[1] = (int)(c4.x * 15.0f); qc[2] = (int)(c4.y * 15.0f);
        qc[3] = (int)(c4.z * 15.0f); qc[4] = (int)(c4.w * 15.0f);
        qu[0] = (int)(um1 * 15.0f);
        qu[1] = (int)(u4.x * 15.0f); qu[2] = (int)(u4.y * 15.0f);
        qu[3] = (int)(u4.z * 15.0f); qu[4] = (int)(u4.w * 15.0f);
        qu[5] = (int)(up4 * 15.0f);

        #pragma unroll
        for (int k = 0; k < 4; ++k) {
            const int q = qc[k + 1];
            const int kb = ((q & 7) << 10) + lane;      // base word for this pixel
            const unsigned int val = 1u << ((q & 8) << 1);  // field = q>>3
            atomicAdd(&lh[kb + (qc[k]     << 6)], val);  // angle   0 (left)
            atomicAdd(&lh[kb + (qu[k + 2] << 6)], val);  // angle  45 (up-right)
            atomicAdd(&lh[kb + (qu[k + 1] << 6)], val);  // angle  90 (up)
            atomicAdd(&lh[kb + (qu[k]     << 6)], val);  // angle 135 (up-left)
        }

        c4 = nc4; u4 = nu4; cm1 = ncm1; um1 = num1; up4 = nup4;
    }

    __syncthreads();
    // Merge: thread t sums pair-column p = t&127 over lane half (t>>7).
    // p = (q&7)*16+s: low field -> bin p, high field -> bin p+128.
    // Rotated lane order keeps each wave's reads conflict-free.
    const int p  = tid & 127;
    const int hf = tid >> 7;
    unsigned int slo = 0, shi = 0;
    #pragma unroll
    for (int i = 0; i < 32; ++i) {
        const int l = (hf << 5) + ((p + i) & 31);
        const unsigned int w = lh[(p << 6) + l];
        slo += w & 0xffffu;
        shi += w >> 16;
    }
    __syncthreads();                 // lh reads done; reuse lh[0..255] as scratch
    if (hf) { lh[p] = slo; lh[128 + p] = shi; }
    __syncthreads();
    if (!hf) {
        const size_t ob = (size_t)(img * NSTRIPS + strip) * NBINS;
        partial[ob + p]       = slo + lh[p];
        partial[ob + 128 + p] = shi + lh[128 + p];
    }
}

// ---------------------------------------------------------------------------
// Kernel 2: fused entropy + broadcast-fill. 2048 blocks = 128 images x 16.
// Each block redundantly computes its image's entropy from the 8 strip
// partials (L2-hot), then fills its 1/16 slice with nontemporal stores.
// counts.sum() == 4*H*W == 2^20 exactly. At ~22us this sits on the HBM
// write-BW floor (134MB at ~6.5 TB/s; harness fills peak at 6.9-7.1).
// ---------------------------------------------------------------------------
__global__ __launch_bounds__(256) void glcm_entfill_kernel(
    const unsigned int* __restrict__ partial, float* __restrict__ out) {

    __shared__ float psum[4];
    __shared__ float ent_s;
    const int tid = threadIdx.x;
    const int bid = blockIdx.x;
    const int img = bid >> 4;
    const int sub = bid & 15;

    unsigned int c = 0;
    #pragma unroll
    for (int s = 0; s < NSTRIPS; ++s)
        c += partial[(size_t)(img * NSTRIPS + s) * NBINS + tid];

    const float p = (float)c * (1.0f / 1048576.0f);   // exact pow2 scale
    float t = p * logf(p + 1e-10f);
    #pragma unroll
    for (int off = 32; off > 0; off >>= 1) t += __shfl_down(t, off, 64);
    if ((tid & 63) == 0) psum[tid >> 6] = t;
    __syncthreads();
    if (tid == 0) ent_s = -(psum[0] + psum[1] + psum[2] + psum[3]);
    __syncthreads();

    const float e = ent_s;
    const f32x4 v = {e, e, e, e};
    f32x4* ob = reinterpret_cast<f32x4*>(out) +
                (size_t)img * (IMG_HW / 4) + (size_t)sub * (IMG_HW / 4 / FILL_PER_IMG);
    #pragma unroll
    for (int i = tid; i < IMG_HW / 4 / FILL_PER_IMG; i += 256)   // 16 stores/thread
        __builtin_nontemporal_store(v, ob + i);
}

extern "C" void kernel_launch(void* const* d_in, const int* in_sizes, int n_in,
                              void* d_out, int out_size, void* d_ws, size_t ws_size,
                              hipStream_t stream) {
    const float* x = (const float*)d_in[0];
    float* out = (float*)d_out;
    unsigned int* partial = (unsigned int*)d_ws;   // 128*8*256 u32 = 1 MB

    glcm_hist_kernel<<<N_IMG * NSTRIPS, 256, 0, stream>>>(x, partial);
    glcm_entfill_kernel<<<N_IMG * FILL_PER_IMG, 256, 0, stream>>>(partial, out);
}